// Round 3
// baseline (7158.234 us; speedup 1.0000x reference)
//
#include <hip/hip_runtime.h>
#include <cstdint>
#include <cstddef>

#define A_N 100000
#define B_N 200000
#define M_N 20000
#define HD 256
#define MAX_NB 10
#define N_MOLS 2000
#define ATOM_FDIM 35
#define FB_DIM 40

#define BM 64
#define BN 128
#define BK 32

// Static device buffers — avoids any assumption about ws_size.
// Allocated at module load (BSS). 2 x 204.8 MB ping-pong message buffers.
__device__ float g_msg0[(size_t)B_N * HD];
__device__ float g_msg1[(size_t)B_N * HD];
__device__ float g_counts[N_MOLS];

// ---------------- zero fill ----------------
__global__ __launch_bounds__(256)
void k_zero_out(float* __restrict__ p, int n)
{
    const int i = blockIdx.x * 256 + threadIdx.x;
    if (i < n) p[i] = 0.f;
}

__global__ __launch_bounds__(256)
void k_zero_counts()
{
    const int i = blockIdx.x * 256 + threadIdx.x;
    if (i < N_MOLS) g_counts[i] = 0.f;
}

// ---------------- K1: g_msg0 = relu(fbonds @ W_i) ----------------
__global__ __launch_bounds__(256)
void k_in(const float* __restrict__ fbonds, const float* __restrict__ Wi)
{
    __shared__ float Ws[FB_DIM * HD];                      // 40 KB
    for (int i = threadIdx.x; i < FB_DIM * HD; i += 256) Ws[i] = Wi[i];
    __syncthreads();
    const int lane = threadIdx.x & 63;
    const int wid  = (blockIdx.x * 256 + threadIdx.x) >> 6;
    const int nw   = (gridDim.x * 256) >> 6;
    for (int row = wid; row < B_N; row += nw) {
        const float* fr = fbonds + (size_t)row * FB_DIM;
        float f[FB_DIM];
        #pragma unroll
        for (int q = 0; q < FB_DIM / 4; ++q) {
            const float4 v = *(const float4*)(fr + q * 4);
            f[q*4+0] = v.x; f[q*4+1] = v.y; f[q*4+2] = v.z; f[q*4+3] = v.w;
        }
        float ax = 0.f, ay = 0.f, az = 0.f, aw = 0.f;
        #pragma unroll
        for (int k = 0; k < FB_DIM; ++k) {
            const float4 w = *(const float4*)&Ws[k * HD + lane * 4];
            ax += f[k] * w.x; ay += f[k] * w.y; az += f[k] * w.z; aw += f[k] * w.w;
        }
        float4 r; r.x = fmaxf(ax, 0.f); r.y = fmaxf(ay, 0.f);
        r.z = fmaxf(az, 0.f); r.w = fmaxf(aw, 0.f);
        *(float4*)(g_msg0 + (size_t)row * HD + lane * 4) = r;
    }
}

// ------- K2 (x2): dst = relu(fbonds@W_i + gather(bgraph,[tmsg;src]) @ W_h) -------
// gather fused into A-tile staging; binput recomputed in epilogue from LDS W_i
// srcSel: 0 -> read g_msg0, write g_msg1 ; 1 -> read g_msg1, write g_msg0
__global__ __launch_bounds__(256)
void k_mp(const int* __restrict__ bgraph, const float* __restrict__ tmsg,
          const float* __restrict__ Wh, const float* __restrict__ fbonds,
          const float* __restrict__ Wi, int srcSel)
{
    const float* gsrc = srcSel ? g_msg1 : g_msg0;
    float* gdst       = srcSel ? g_msg0 : g_msg1;

    __shared__ float As[BK][BM + 4];       // 8.5 KB
    __shared__ float Bs[BK][BN + 4];       // 16.5 KB
    __shared__ float wi_s[FB_DIM][BN];     // 20 KB (epilogue W_i tile)
    const int tid = threadIdx.x;
    const int rowBase = blockIdx.x * BM;
    const int colBase = blockIdx.y * BN;

    // stage W_i tile for epilogue: 40x128 floats = 1280 float4, 5 per thread
    #pragma unroll
    for (int i = 0; i < 5; ++i) {
        const int idx = tid + i * 256;     // [0,1280)
        const int k = idx >> 5;            // [0,40)
        const int c = (idx & 31) << 2;     // [0,128)
        *(float4*)&wi_s[k][c] = *(const float4*)(Wi + (size_t)k * HD + colBase + c);
    }

    // resolve neighbor pointers for this thread's two A-tile rows (hoisted)
    const int r0 = tid >> 3;               // [0,32)
    const int kq = (tid & 7) << 2;         // {0,4,...,28}
    const float* p0[MAX_NB];
    const float* p1[MAX_NB];
    {
        const int* ga = bgraph + (size_t)(rowBase + r0) * MAX_NB;
        const int* gb = bgraph + (size_t)(rowBase + r0 + 32) * MAX_NB;
        #pragma unroll
        for (int j = 0; j < MAX_NB; ++j) {
            const int a = ga[j];
            const int b = gb[j];
            p0[j] = (a < M_N) ? (tmsg + (size_t)a * HD) : (gsrc + (size_t)(a - M_N) * HD);
            p1[j] = (b < M_N) ? (tmsg + (size_t)b * HD) : (gsrc + (size_t)(b - M_N) * HD);
        }
    }

    const int tx = tid & 15;
    const int ty = tid >> 4;
    float acc[4][8] = {};

    for (int k0 = 0; k0 < HD; k0 += BK) {
        // A-tile: gather-sum of 10 neighbor rows, float4 per (row, k-quad)
        float4 s0 = {0.f, 0.f, 0.f, 0.f};
        float4 s1 = {0.f, 0.f, 0.f, 0.f};
        #pragma unroll
        for (int j = 0; j < MAX_NB; ++j) {
            const float4 v0 = *(const float4*)(p0[j] + k0 + kq);
            const float4 v1 = *(const float4*)(p1[j] + k0 + kq);
            s0.x += v0.x; s0.y += v0.y; s0.z += v0.z; s0.w += v0.w;
            s1.x += v1.x; s1.y += v1.y; s1.z += v1.z; s1.w += v1.w;
        }
        As[kq + 0][r0] = s0.x; As[kq + 1][r0] = s0.y;
        As[kq + 2][r0] = s0.z; As[kq + 3][r0] = s0.w;
        As[kq + 0][r0 + 32] = s1.x; As[kq + 1][r0 + 32] = s1.y;
        As[kq + 2][r0 + 32] = s1.z; As[kq + 3][r0 + 32] = s1.w;
        // B-tile
        #pragma unroll
        for (int i = 0; i < 4; ++i) {
            const int idx = tid + i * 256;
            const int kk = idx >> 5;
            const int c = (idx & 31) << 2;
            *(float4*)&Bs[kk][c] = *(const float4*)(Wh + (size_t)(k0 + kk) * HD + colBase + c);
        }
        __syncthreads();
        #pragma unroll
        for (int kk = 0; kk < BK; ++kk) {
            const float4 a  = *(const float4*)&As[kk][ty * 4];
            const float4 b0 = *(const float4*)&Bs[kk][tx * 4];
            const float4 b1 = *(const float4*)&Bs[kk][64 + tx * 4];
            const float av[4] = {a.x, a.y, a.z, a.w};
            const float bv[8] = {b0.x, b0.y, b0.z, b0.w, b1.x, b1.y, b1.z, b1.w};
            #pragma unroll
            for (int i = 0; i < 4; ++i)
                #pragma unroll
                for (int j = 0; j < 8; ++j)
                    acc[i][j] += av[i] * bv[j];
        }
        __syncthreads();
    }

    // epilogue: acc += fbonds_row @ W_i (binput recompute), then relu + store
    #pragma unroll
    for (int i = 0; i < 4; ++i) {
        const int r = rowBase + ty * 4 + i;
        const float* fr = fbonds + (size_t)r * FB_DIM;
        float f[FB_DIM];
        #pragma unroll
        for (int q = 0; q < FB_DIM / 4; ++q) {
            const float4 v = *(const float4*)(fr + q * 4);
            f[q*4+0] = v.x; f[q*4+1] = v.y; f[q*4+2] = v.z; f[q*4+3] = v.w;
        }
        #pragma unroll
        for (int k = 0; k < FB_DIM; ++k) {
            const float4 b0 = *(const float4*)&wi_s[k][tx * 4];
            const float4 b1 = *(const float4*)&wi_s[k][64 + tx * 4];
            acc[i][0] += f[k] * b0.x; acc[i][1] += f[k] * b0.y;
            acc[i][2] += f[k] * b0.z; acc[i][3] += f[k] * b0.w;
            acc[i][4] += f[k] * b1.x; acc[i][5] += f[k] * b1.y;
            acc[i][6] += f[k] * b1.z; acc[i][7] += f[k] * b1.w;
        }
        const size_t base = (size_t)r * HD + colBase;
        float4 o0, o1;
        o0.x = fmaxf(acc[i][0], 0.f); o0.y = fmaxf(acc[i][1], 0.f);
        o0.z = fmaxf(acc[i][2], 0.f); o0.w = fmaxf(acc[i][3], 0.f);
        o1.x = fmaxf(acc[i][4], 0.f); o1.y = fmaxf(acc[i][5], 0.f);
        o1.z = fmaxf(acc[i][6], 0.f); o1.w = fmaxf(acc[i][7], 0.f);
        *(float4*)(gdst + base + tx * 4) = o0;
        *(float4*)(gdst + base + 64 + tx * 4) = o1;
    }
}

// ------- K3: out += segsum(relu([fatoms|gather(agraph,msg)] @ W_o + b)) -------
// message pool = [tmsg ; g_msg0] (g_msg0 holds final graph_message after 2 k_mp)
// virtual A layout (K=320): [0,35)=fatoms, [35,40)=0, [40,296)=gather, [296,320)=0
// B rows remapped to match: kg<35 -> Wo[kg]; 40<=kg<296 -> Wo[kg-5]; else 0
__global__ __launch_bounds__(256)
void k_final(const int* __restrict__ agraph, const float* __restrict__ tmsg,
             const float* __restrict__ fatoms, const float* __restrict__ Wo,
             const float* __restrict__ bias, const int* __restrict__ scope,
             float* __restrict__ outsum)
{
    const float* gm = g_msg0;
    __shared__ float As[BK][BM + 4];
    __shared__ float Bs[BK][BN + 4];
    const int tid = threadIdx.x;
    const int rowBase = blockIdx.x * BM;
    const int colBase = blockIdx.y * BN;

    const int r0 = tid >> 3;
    const int kq = (tid & 7) << 2;
    const int ra0 = rowBase + r0;
    const int ra1 = rowBase + r0 + 32;
    const bool v0 = ra0 < A_N;
    const bool v1 = ra1 < A_N;
    const float* p0[MAX_NB];
    const float* p1[MAX_NB];
    #pragma unroll
    for (int j = 0; j < MAX_NB; ++j) {
        const int a = v0 ? agraph[(size_t)ra0 * MAX_NB + j] : 0;
        const int b = v1 ? agraph[(size_t)ra1 * MAX_NB + j] : 0;
        p0[j] = (a < M_N) ? (tmsg + (size_t)a * HD) : (gm + (size_t)(a - M_N) * HD);
        p1[j] = (b < M_N) ? (tmsg + (size_t)b * HD) : (gm + (size_t)(b - M_N) * HD);
    }

    const int tx = tid & 15;
    const int ty = tid >> 4;
    float acc[4][8] = {};

    for (int k0 = 0; k0 < 320; k0 += BK) {
        const int k = k0 + kq;
        float4 s0 = {0.f, 0.f, 0.f, 0.f};
        float4 s1 = {0.f, 0.f, 0.f, 0.f};
        if (k >= 40 && k < 296) {
            const int off = k - 40;
            if (v0) {
                #pragma unroll
                for (int j = 0; j < MAX_NB; ++j) {
                    const float4 v = *(const float4*)(p0[j] + off);
                    s0.x += v.x; s0.y += v.y; s0.z += v.z; s0.w += v.w;
                }
            }
            if (v1) {
                #pragma unroll
                for (int j = 0; j < MAX_NB; ++j) {
                    const float4 v = *(const float4*)(p1[j] + off);
                    s1.x += v.x; s1.y += v.y; s1.z += v.z; s1.w += v.w;
                }
            }
        } else if (k < 40) {
            #pragma unroll
            for (int q = 0; q < 4; ++q) {
                const int kk = k + q;
                float x0 = 0.f, x1 = 0.f;
                if (kk < ATOM_FDIM) {
                    if (v0) x0 = fatoms[(size_t)ra0 * ATOM_FDIM + kk];
                    if (v1) x1 = fatoms[(size_t)ra1 * ATOM_FDIM + kk];
                }
                ((float*)&s0)[q] = x0;
                ((float*)&s1)[q] = x1;
            }
        }
        As[kq + 0][r0] = s0.x; As[kq + 1][r0] = s0.y;
        As[kq + 2][r0] = s0.z; As[kq + 3][r0] = s0.w;
        As[kq + 0][r0 + 32] = s1.x; As[kq + 1][r0 + 32] = s1.y;
        As[kq + 2][r0 + 32] = s1.z; As[kq + 3][r0 + 32] = s1.w;
        #pragma unroll
        for (int i = 0; i < 4; ++i) {
            const int idx = tid + i * 256;
            const int kk = idx >> 5;
            const int c = (idx & 31) << 2;
            const int kg = k0 + kk;
            float4 v = {0.f, 0.f, 0.f, 0.f};
            if (kg < ATOM_FDIM)
                v = *(const float4*)(Wo + (size_t)kg * HD + colBase + c);
            else if (kg >= 40 && kg < 296)
                v = *(const float4*)(Wo + (size_t)(kg - 5) * HD + colBase + c);
            *(float4*)&Bs[kk][c] = v;
        }
        __syncthreads();
        #pragma unroll
        for (int kk = 0; kk < BK; ++kk) {
            const float4 a  = *(const float4*)&As[kk][ty * 4];
            const float4 b0 = *(const float4*)&Bs[kk][tx * 4];
            const float4 b1 = *(const float4*)&Bs[kk][64 + tx * 4];
            const float av[4] = {a.x, a.y, a.z, a.w};
            const float bv[8] = {b0.x, b0.y, b0.z, b0.w, b1.x, b1.y, b1.z, b1.w};
            #pragma unroll
            for (int i = 0; i < 4; ++i)
                #pragma unroll
                for (int j = 0; j < 8; ++j)
                    acc[i][j] += av[i] * bv[j];
        }
        __syncthreads();
    }

    const float4 bb0 = *(const float4*)(bias + colBase + tx * 4);
    const float4 bb1 = *(const float4*)(bias + colBase + 64 + tx * 4);
    const float bb[8] = {bb0.x, bb0.y, bb0.z, bb0.w, bb1.x, bb1.y, bb1.z, bb1.w};
    float s[8] = {0.f, 0.f, 0.f, 0.f, 0.f, 0.f, 0.f, 0.f};
    int prev = -1;
    #pragma unroll
    for (int i = 0; i < 4; ++i) {
        const int r = rowBase + ty * 4 + i;
        if (r < A_N) {
            const int m = scope[r];
            if (m != prev) {
                if (prev >= 0) {
                    float* dst = outsum + (size_t)prev * HD + colBase;
                    #pragma unroll
                    for (int q = 0; q < 4; ++q) {
                        atomicAdd(dst + tx * 4 + q, s[q]);
                        atomicAdd(dst + 64 + tx * 4 + q, s[4 + q]);
                    }
                    #pragma unroll
                    for (int q = 0; q < 8; ++q) s[q] = 0.f;
                }
                prev = m;
            }
            #pragma unroll
            for (int q = 0; q < 8; ++q)
                s[q] += fmaxf(acc[i][q] + bb[q], 0.f);
        }
    }
    if (prev >= 0) {
        float* dst = outsum + (size_t)prev * HD + colBase;
        #pragma unroll
        for (int q = 0; q < 4; ++q) {
            atomicAdd(dst + tx * 4 + q, s[q]);
            atomicAdd(dst + 64 + tx * 4 + q, s[4 + q]);
        }
    }
}

// ---------------- counts + divide ----------------
__global__ __launch_bounds__(256)
void k_counts(const int* __restrict__ scope)
{
    const int a = blockIdx.x * 256 + threadIdx.x;
    if (a < A_N) atomicAdd(&g_counts[scope[a]], 1.0f);
}

__global__ __launch_bounds__(256)
void k_div(float* __restrict__ out)
{
    const int idx = blockIdx.x * 256 + threadIdx.x;
    out[idx] = out[idx] / fmaxf(g_counts[idx >> 8], 1.0f);
}

// ---------------- launch ----------------
extern "C" void kernel_launch(void* const* d_in, const int* in_sizes, int n_in,
                              void* d_out, int out_size, void* d_ws, size_t ws_size,
                              hipStream_t stream)
{
    const float* fatoms = (const float*)d_in[0];
    const float* fbonds = (const float*)d_in[1];
    const int*   agraph = (const int*)d_in[2];
    const int*   bgraph = (const int*)d_in[3];
    const float* tmsg   = (const float*)d_in[4];
    const int*   scope  = (const int*)d_in[5];
    const float* W_i    = (const float*)d_in[6];
    const float* W_h    = (const float*)d_in[7];
    const float* W_o    = (const float*)d_in[8];
    const float* W_ob   = (const float*)d_in[9];
    float* out = (float*)d_out;

    (void)d_ws; (void)ws_size;  // unused — buffers are static __device__ globals

    k_zero_out<<<(N_MOLS * HD + 255) / 256, 256, 0, stream>>>(out, N_MOLS * HD);
    k_zero_counts<<<(N_MOLS + 255) / 256, 256, 0, stream>>>();

    k_in<<<4096, 256, 0, stream>>>(fbonds, W_i);
    k_mp<<<dim3(B_N / BM, HD / BN), 256, 0, stream>>>(bgraph, tmsg, W_h, fbonds, W_i, 0);
    k_mp<<<dim3(B_N / BM, HD / BN), 256, 0, stream>>>(bgraph, tmsg, W_h, fbonds, W_i, 1);
    k_counts<<<(A_N + 255) / 256, 256, 0, stream>>>(scope);
    k_final<<<dim3((A_N + BM - 1) / BM, HD / BN), 256, 0, stream>>>(agraph, tmsg, fatoms, W_o, W_ob, scope, out);
    k_div<<<(N_MOLS * HD) / 256, 256, 0, stream>>>(out);
}